// Round 2
// baseline (507.035 us; speedup 1.0000x reference)
//
#include <hip/hip_runtime.h>

// TMoE layer: y = SCALING * (softmax(x@route_w^T) gated low-rank mixture)
// R5 factorization change: g is NEVER materialized.
//   k1: c[t][r] = x@A^T (f32), route[t][e] = softmax(x@Rw^T)*SCALING (f32)
//   k2: y = (route-gated expansion of c) @ Bflat^T, with A-frags built
//       in-register from LDS-resident c/route tiles: af = bf16(route*c).
// This removes the 33MB g write + 268MB g re-read of R4, and k1's K-loop
// gets explicit depth-3 (x/HBM) + depth-2 (w1/L2) register prefetch to fix
// the VGPR=36 serial-load-chain pathology (R4 counters: HBM 15%, all pipes
// idle). k2 main loop has NO barriers: c/route staged once, bc B-frags
// loaded straight from L2 with depth-2 prefetch.

#define NTOK    32768
#define DIM     1024
#define NW1     80          // 64 c-rows + 8 router rows + 8 zero pad
#define GDIM    512         // E*R
#define OUTD    1024
#define SCALING 0.25f

typedef __bf16 bf16x8 __attribute__((ext_vector_type(8)));
typedef float  f32x4  __attribute__((ext_vector_type(4)));

static __device__ __forceinline__ unsigned short f2bf(float f) {
    union { float f; unsigned u; } v; v.f = f;
    unsigned r = v.u + 0x7FFFu + ((v.u >> 16) & 1u);   // RNE
    return (unsigned short)(r >> 16);
}

// ---------------- weight conversion (R0-proven, unchanged) ----------------
__global__ __launch_bounds__(256) void conv_w1(const float* __restrict__ A,
                                               const float* __restrict__ Rw,
                                               unsigned short* __restrict__ w1) {
    int i = blockIdx.x * 256 + threadIdx.x;
    if (i >= NW1 * DIM) return;
    int row = i >> 10, col = i & (DIM - 1);
    float v = 0.0f;
    if (row < 64)      v = A[(row << 10) + col];
    else if (row < 72) v = Rw[((row - 64) << 10) + col];
    w1[i] = f2bf(v);
}

__global__ __launch_bounds__(256) void conv_b(const float* __restrict__ B,
                                              unsigned short* __restrict__ bc) {
    int i = blockIdx.x * 256 + threadIdx.x;     // i = o*512 + e*64 + r
    if (i >= OUTD * GDIM) return;
    int o = i >> 9, er = i & 511;
    int e = er >> 6, r = er & 63;
    bc[i] = f2bf(B[(e << 16) + (o << 6) + r]);  // B[e][o][r], strides 65536/64/1
}

// ---------------- k1: routing + compress (R5) ----------------
// 32 tok/block, 4 waves = (2 token groups) x (2 K-halves). Barrier-free
// K-loop with explicit register prefetch: x depth-3 (HBM), w1 depth-2 (L2).
// Outputs: cout f32 [NTOK][64] (sum of K-halves), rout f32 [NTOK][8]
// (softmax * SCALING). One barrier total.
__global__ __launch_bounds__(256, 4) void k1_route_compress(
        const float* __restrict__ x,
        const unsigned short* __restrict__ w1,
        float* __restrict__ cout,
        float* __restrict__ rout) {
    __shared__ float cAll[2][32][84];

    const int tid  = threadIdx.x;
    const int wave = tid >> 6;
    const int lane = tid & 63;
    const int quad = lane >> 4;
    const int l16  = lane & 15;
    const int t0   = blockIdx.x << 5;          // 32 tokens/block

    const int tokw  = (wave >> 1) << 4;        // 0 or 16
    const int khalf = wave & 1;                // K-half this wave owns
    const int kb0   = khalf << 9;              // 0 or 512

    f32x4 acc[5];
#pragma unroll
    for (int n = 0; n < 5; ++n) acc[n] = (f32x4){0.f, 0.f, 0.f, 0.f};

    // per-lane bases matching the 16x16x32 A/B fragment layout
    const float* xp = x + (size_t)(t0 + tokw + l16) * DIM + kb0 + (quad << 3);
    const unsigned short* wp = w1 + (l16 << 10) + kb0 + (quad << 3);

    // rotating prefetch slots (statically indexed after full unroll)
    float4 xa[3], xb[3];
    bf16x8 wv[2][5];
#pragma unroll
    for (int s = 0; s < 3; ++s) {
        xa[s] = *(const float4*)(xp + (s << 5));
        xb[s] = *(const float4*)(xp + (s << 5) + 4);
    }
#pragma unroll
    for (int s = 0; s < 2; ++s)
#pragma unroll
        for (int n = 0; n < 5; ++n)
            wv[s][n] = *(const bf16x8*)(wp + (n << 14) + (s << 5));

#pragma unroll
    for (int kk = 0; kk < 16; ++kk) {
        const int sx = kk % 3;
        const int sw = kk & 1;
        // SSA copies so prefetch stores can issue before the cvt chain
        const float4 ca = xa[sx];
        const float4 cb = xb[sx];
        bf16x8 bfr[5];
#pragma unroll
        for (int n = 0; n < 5; ++n) bfr[n] = wv[sw][n];

        if (kk + 3 < 16) {
            xa[sx] = *(const float4*)(xp + ((kk + 3) << 5));
            xb[sx] = *(const float4*)(xp + ((kk + 3) << 5) + 4);
        }
        if (kk + 2 < 16) {
#pragma unroll
            for (int n = 0; n < 5; ++n)
                wv[sw][n] = *(const bf16x8*)(wp + (n << 14) + ((kk + 2) << 5));
        }

        bf16x8 af;
        af[0] = (__bf16)ca.x; af[1] = (__bf16)ca.y;
        af[2] = (__bf16)ca.z; af[3] = (__bf16)ca.w;
        af[4] = (__bf16)cb.x; af[5] = (__bf16)cb.y;
        af[6] = (__bf16)cb.z; af[7] = (__bf16)cb.w;
#pragma unroll
        for (int n = 0; n < 5; ++n)
            acc[n] = __builtin_amdgcn_mfma_f32_16x16x32_bf16(af, bfr[n], acc[n], 0, 0, 0);
    }

    // D layout: col = lane&15 (token), row = quad*4 + reg (feature)
#pragma unroll
    for (int n = 0; n < 5; ++n)
#pragma unroll
        for (int r = 0; r < 4; ++r)
            cAll[khalf][tokw + (quad << 2) + r][(n << 4) + l16] = acc[n][r];
    __syncthreads();

    if (tid < 32) {
        float lg[8]; float m = -1e30f;
#pragma unroll
        for (int e = 0; e < 8; ++e) {
            lg[e] = cAll[0][tid][64 + e] + cAll[1][tid][64 + e];
            m = fmaxf(m, lg[e]);
        }
        float s = 0.f;
#pragma unroll
        for (int e = 0; e < 8; ++e) { lg[e] = expf(lg[e] - m); s += lg[e]; }
        float inv = SCALING / s;
        float4 r0v = (float4){lg[0] * inv, lg[1] * inv, lg[2] * inv, lg[3] * inv};
        float4 r1v = (float4){lg[4] * inv, lg[5] * inv, lg[6] * inv, lg[7] * inv};
        float* rp = rout + (size_t)(t0 + tid) * 8;
        *(float4*)(rp)     = r0v;
        *(float4*)(rp + 4) = r1v;
    }

    // c write: 32 tok x 64 f32 = 256 threads x 8 f32
    {
        int t  = tid >> 3;
        int c0 = (tid & 7) << 3;
        f32x4 a0 = *(const f32x4*)&cAll[0][t][c0];
        f32x4 a1 = *(const f32x4*)&cAll[0][t][c0 + 4];
        f32x4 b0 = *(const f32x4*)&cAll[1][t][c0];
        f32x4 b1 = *(const f32x4*)&cAll[1][t][c0 + 4];
        f32x4 s0 = a0 + b0, s1 = a1 + b1;
        float* cp = cout + (size_t)(t0 + t) * 64 + c0;
        *(f32x4*)(cp)     = s0;
        *(f32x4*)(cp + 4) = s1;
    }
}

// ---------------- k2: y = gated(c,route) @ Bflat^T (R5) ----------------
// 128x128 tile, 4 waves x 64x64. c/route tiles staged ONCE into LDS
// (sc stride 68 dwords -> 2 lanes/bank on b128 reads; sr stride 9 ->
// conflict-free). Main loop: build af = bf16(route*c) in registers,
// B-frags direct from L2-resident bc with depth-2 prefetch. No barriers
// in the K loop.
__global__ __launch_bounds__(256, 3) void k2_up(
        const float* __restrict__ cw,
        const float* __restrict__ rt,
        const unsigned short* __restrict__ bc,
        float* __restrict__ y) {
    __shared__ float sc[128][68];
    __shared__ float sr[128][9];

    const int tid  = threadIdx.x;
    const int wave = tid >> 6;
    const int lane = tid & 63;
    const int quad = lane >> 4;
    const int l16  = lane & 15;

    const int m0 = (blockIdx.x & 255) << 7;
    const int n0 = (blockIdx.x >> 8) << 7;
    const int mo = (wave & 1) << 6;
    const int no = (wave >> 1) << 6;

    // stage c tile: 128 x 64 f32
#pragma unroll
    for (int i = 0; i < 8; ++i) {
        int idx = tid + (i << 8);        // 0..2047
        int row = idx >> 4, q = idx & 15;
        *(f32x4*)&sc[row][q << 2] =
            *(const f32x4*)(cw + (size_t)(m0 + row) * 64 + (q << 2));
    }
    // stage route tile: 128 x 8 f32
#pragma unroll
    for (int i = 0; i < 4; ++i) {
        int idx = tid + (i << 8);        // 0..1023
        int row = idx >> 3, e = idx & 7;
        sr[row][e] = rt[(size_t)(m0 + row) * 8 + e];
    }
    __syncthreads();

    f32x4 acc[4][4];
#pragma unroll
    for (int i = 0; i < 4; ++i)
#pragma unroll
        for (int j = 0; j < 4; ++j) acc[i][j] = (f32x4){0.f, 0.f, 0.f, 0.f};

    const unsigned short* bp = bc + (size_t)(n0 + no + l16) * GDIM + (quad << 3);

    bf16x8 bcur[4], bnxt[4];
#pragma unroll
    for (int j = 0; j < 4; ++j)
        bcur[j] = *(const bf16x8*)(bp + (j << 13));          // j*16*GDIM

#pragma unroll 4
    for (int kk = 0; kk < 16; ++kk) {
        if (kk < 15) {
#pragma unroll
            for (int j = 0; j < 4; ++j)
                bnxt[j] = *(const bf16x8*)(bp + (j << 13) + ((kk + 1) << 5));
        }
        const int r0 = ((kk & 1) << 5) + (quad << 3);        // dword idx in c row
        const int e  = kk >> 1;                              // uniform expert idx
        bf16x8 afr[4];
#pragma unroll
        for (int i = 0; i < 4; ++i) {
            int row = mo + (i << 4) + l16;
            f32x4 c0 = *(const f32x4*)&sc[row][r0];
            f32x4 c1 = *(const f32x4*)&sc[row][r0 + 4];
            float rv = sr[row][e];
#pragma unroll
            for (int j2 = 0; j2 < 4; ++j2) {
                afr[i][j2]     = (__bf16)(rv * c0[j2]);
                afr[i][4 + j2] = (__bf16)(rv * c1[j2]);
            }
        }
#pragma unroll
        for (int i = 0; i < 4; ++i)
#pragma unroll
            for (int j = 0; j < 4; ++j)
                acc[i][j] = __builtin_amdgcn_mfma_f32_16x16x32_bf16(afr[i], bcur[j], acc[i][j], 0, 0, 0);
#pragma unroll
        for (int j = 0; j < 4; ++j) bcur[j] = bnxt[j];
    }

#pragma unroll
    for (int i = 0; i < 4; ++i)
#pragma unroll
        for (int j = 0; j < 4; ++j)
#pragma unroll
            for (int r = 0; r < 4; ++r) {
                int row = m0 + mo + (i << 4) + (quad << 2) + r;
                int col = n0 + no + (j << 4) + l16;
                y[(size_t)row * OUTD + col] = acc[i][j][r];
            }
}

extern "C" void kernel_launch(void* const* d_in, const int* in_sizes, int n_in,
                              void* d_out, int out_size, void* d_ws, size_t ws_size,
                              hipStream_t stream) {
    const float* x  = (const float*)d_in[0];   // [8,4096,1024]
    const float* rw = (const float*)d_in[1];   // [8,1024]
    const float* A  = (const float*)d_in[2];   // [64,1024]
    const float* B  = (const float*)d_in[3];   // [8,1024,64]
    float* y = (float*)d_out;                  // [8,4096,1024] fp32

    float* cw = (float*)d_ws;                          // [32768][64] f32
    float* rt = cw + (size_t)NTOK * 64;                // [32768][8] f32
    unsigned short* w1 = (unsigned short*)(rt + (size_t)NTOK * 8);  // [80][1024] bf16
    unsigned short* bc = w1 + NW1 * DIM;               // [1024][512] bf16

    conv_w1<<<(NW1 * DIM + 255) / 256, 256, 0, stream>>>(A, rw, w1);
    conv_b<<<(OUTD * GDIM + 255) / 256, 256, 0, stream>>>(B, bc);
    k1_route_compress<<<NTOK / 32, 256, 0, stream>>>(x, w1, cw, rt);
    k2_up<<<(NTOK / 128) * (OUTD / 128), 256, 0, stream>>>(cw, rt, bc, y);
}

// Round 3
// 314.160 us; speedup vs baseline: 1.6139x; 1.6139x over previous
//
#include <hip/hip_runtime.h>

// TMoE layer: y = SCALING * (softmax(x@route_w^T) gated low-rank mixture)
// R6: keep R5's factorization (g never materialized; k1 emits c[t][64] f32 +
// route[t][8] f32 pre-scaled), but revert k2 to the R3-PROVEN 2-barrier
// LDS-staged schedule. R5's k2 spilled (VGPR 84 vs ~130 live: explicit
// bcur/bnxt double-buffer x unroll-4 -> scratch -> 900MB of phantom HBM
// traffic, 278us). R6 k2 stages the GATED A-tile per k0-chunk:
//   sA[row][r] = bf16(route[row][k0>>6] * c[row][r])
// (c tile is 32KB, L1-hot across the 8 chunks; e is uniform per chunk),
// B staged from L2-resident bc exactly as R3. MFMA loop bit-identical to R3.
// k1: single bounded change vs R5 — x prefetch depth 3 -> 4 (VGPR ~105 < 128
// cap at 4 blocks/CU). k1 is latency-bound (all pipes <5%, eff. read 1.6TB/s);
// per-wave in-flight bytes is the lever under test.

#define NTOK    32768
#define DIM     1024
#define NW1     80          // 64 c-rows + 8 router rows + 8 zero pad
#define GDIM    512         // E*R
#define OUTD    1024
#define SCALING 0.25f

typedef __bf16 bf16x8 __attribute__((ext_vector_type(8)));
typedef float  f32x4  __attribute__((ext_vector_type(4)));

static __device__ __forceinline__ unsigned short f2bf(float f) {
    union { float f; unsigned u; } v; v.f = f;
    unsigned r = v.u + 0x7FFFu + ((v.u >> 16) & 1u);   // RNE
    return (unsigned short)(r >> 16);
}

// ---------------- weight conversion (R0-proven, unchanged) ----------------
__global__ __launch_bounds__(256) void conv_w1(const float* __restrict__ A,
                                               const float* __restrict__ Rw,
                                               unsigned short* __restrict__ w1) {
    int i = blockIdx.x * 256 + threadIdx.x;
    if (i >= NW1 * DIM) return;
    int row = i >> 10, col = i & (DIM - 1);
    float v = 0.0f;
    if (row < 64)      v = A[(row << 10) + col];
    else if (row < 72) v = Rw[((row - 64) << 10) + col];
    w1[i] = f2bf(v);
}

__global__ __launch_bounds__(256) void conv_b(const float* __restrict__ B,
                                              unsigned short* __restrict__ bc) {
    int i = blockIdx.x * 256 + threadIdx.x;     // i = o*512 + e*64 + r
    if (i >= OUTD * GDIM) return;
    int o = i >> 9, er = i & 511;
    int e = er >> 6, r = er & 63;
    bc[i] = f2bf(B[(e << 16) + (o << 6) + r]);  // B[e][o][r], strides 65536/64/1
}

// ---------------- k1: routing + compress (R6: x depth-4 prefetch) -------
// 32 tok/block, 4 waves = (2 token groups) x (2 K-halves). Barrier-free
// K-loop, register prefetch: x depth-4 (HBM/L3), w1 depth-2 (L2).
// Outputs: cout f32 [NTOK][64] (sum of K-halves), rout f32 [NTOK][8]
// (softmax * SCALING). One barrier total.
__global__ __launch_bounds__(256, 4) void k1_route_compress(
        const float* __restrict__ x,
        const unsigned short* __restrict__ w1,
        float* __restrict__ cout,
        float* __restrict__ rout) {
    __shared__ float cAll[2][32][84];

    const int tid  = threadIdx.x;
    const int wave = tid >> 6;
    const int lane = tid & 63;
    const int quad = lane >> 4;
    const int l16  = lane & 15;
    const int t0   = blockIdx.x << 5;          // 32 tokens/block

    const int tokw  = (wave >> 1) << 4;        // 0 or 16
    const int khalf = wave & 1;                // K-half this wave owns
    const int kb0   = khalf << 9;              // 0 or 512

    f32x4 acc[5];
#pragma unroll
    for (int n = 0; n < 5; ++n) acc[n] = (f32x4){0.f, 0.f, 0.f, 0.f};

    // per-lane bases matching the 16x16x32 A/B fragment layout
    const float* xp = x + (size_t)(t0 + tokw + l16) * DIM + kb0 + (quad << 3);
    const unsigned short* wp = w1 + (l16 << 10) + kb0 + (quad << 3);

    // rotating prefetch slots (statically indexed after full unroll)
    float4 xa[4], xb[4];
    bf16x8 wv[2][5];
#pragma unroll
    for (int s = 0; s < 4; ++s) {
        xa[s] = *(const float4*)(xp + (s << 5));
        xb[s] = *(const float4*)(xp + (s << 5) + 4);
    }
#pragma unroll
    for (int s = 0; s < 2; ++s)
#pragma unroll
        for (int n = 0; n < 5; ++n)
            wv[s][n] = *(const bf16x8*)(wp + (n << 14) + (s << 5));

#pragma unroll
    for (int kk = 0; kk < 16; ++kk) {
        const int sx = kk & 3;
        const int sw = kk & 1;
        // SSA copies so prefetch stores can issue before the cvt chain
        const float4 ca = xa[sx];
        const float4 cb = xb[sx];
        bf16x8 bfr[5];
#pragma unroll
        for (int n = 0; n < 5; ++n) bfr[n] = wv[sw][n];

        if (kk + 4 < 16) {
            xa[sx] = *(const float4*)(xp + ((kk + 4) << 5));
            xb[sx] = *(const float4*)(xp + ((kk + 4) << 5) + 4);
        }
        if (kk + 2 < 16) {
#pragma unroll
            for (int n = 0; n < 5; ++n)
                wv[sw][n] = *(const bf16x8*)(wp + (n << 14) + ((kk + 2) << 5));
        }

        bf16x8 af;
        af[0] = (__bf16)ca.x; af[1] = (__bf16)ca.y;
        af[2] = (__bf16)ca.z; af[3] = (__bf16)ca.w;
        af[4] = (__bf16)cb.x; af[5] = (__bf16)cb.y;
        af[6] = (__bf16)cb.z; af[7] = (__bf16)cb.w;
#pragma unroll
        for (int n = 0; n < 5; ++n)
            acc[n] = __builtin_amdgcn_mfma_f32_16x16x32_bf16(af, bfr[n], acc[n], 0, 0, 0);
    }

    // D layout: col = lane&15 (token), row = quad*4 + reg (feature)
#pragma unroll
    for (int n = 0; n < 5; ++n)
#pragma unroll
        for (int r = 0; r < 4; ++r)
            cAll[khalf][tokw + (quad << 2) + r][(n << 4) + l16] = acc[n][r];
    __syncthreads();

    if (tid < 32) {
        float lg[8]; float m = -1e30f;
#pragma unroll
        for (int e = 0; e < 8; ++e) {
            lg[e] = cAll[0][tid][64 + e] + cAll[1][tid][64 + e];
            m = fmaxf(m, lg[e]);
        }
        float s = 0.f;
#pragma unroll
        for (int e = 0; e < 8; ++e) { lg[e] = expf(lg[e] - m); s += lg[e]; }
        float inv = SCALING / s;
        float4 r0v = (float4){lg[0] * inv, lg[1] * inv, lg[2] * inv, lg[3] * inv};
        float4 r1v = (float4){lg[4] * inv, lg[5] * inv, lg[6] * inv, lg[7] * inv};
        float* rp = rout + (size_t)(t0 + tid) * 8;
        *(float4*)(rp)     = r0v;
        *(float4*)(rp + 4) = r1v;
    }

    // c write: 32 tok x 64 f32 = 256 threads x 8 f32
    {
        int t  = tid >> 3;
        int c0 = (tid & 7) << 3;
        f32x4 a0 = *(const f32x4*)&cAll[0][t][c0];
        f32x4 a1 = *(const f32x4*)&cAll[0][t][c0 + 4];
        f32x4 b0 = *(const f32x4*)&cAll[1][t][c0];
        f32x4 b1 = *(const f32x4*)&cAll[1][t][c0 + 4];
        f32x4 s0 = a0 + b0, s1 = a1 + b1;
        float* cp = cout + (size_t)(t0 + t) * 64 + c0;
        *(f32x4*)(cp)     = s0;
        *(f32x4*)(cp + 4) = s1;
    }
}

// ---------------- k2: y = gated(c,route) @ Bflat^T (R6) ----------------
// R3-proven schedule: 128x128 tile, 4 waves x (64x64 = 4x4 frags), KC=64,
// LDS row stride 72 halfwords (16B aligned), 32 MFMAs per barrier pair.
// Only change vs R3: the sA staging source is gated-c built in-register
// (c f32 tile is L1-hot across the 8 k0 chunks; e = k0>>6 uniform per chunk)
// instead of a pre-materialized g.
__global__ __launch_bounds__(256) void k2_up(
        const float* __restrict__ cw,
        const float* __restrict__ rt,
        const unsigned short* __restrict__ bc,
        float* __restrict__ y) {
    __shared__ unsigned short sA[128][72];
    __shared__ unsigned short sB[128][72];

    const int tid  = threadIdx.x;
    const int wave = tid >> 6;
    const int lane = tid & 63;
    const int quad = lane >> 4;
    const int l16  = lane & 15;

    const int m0 = (blockIdx.x & 255) << 7;
    const int n0 = (blockIdx.x >> 8) << 7;
    const int mo = (wave & 1) << 6;
    const int no = (wave >> 1) << 6;

    f32x4 acc[4][4];
#pragma unroll
    for (int i = 0; i < 4; ++i)
#pragma unroll
        for (int j = 0; j < 4; ++j) acc[i][j] = (f32x4){0.f, 0.f, 0.f, 0.f};

    for (int k0 = 0; k0 < GDIM; k0 += 64) {
        const int e = k0 >> 6;           // uniform expert index for this chunk
        // stage gated A and B: 128 rows x 64 halfwords each; 1024 16B chunks
        // per tile, 4 per thread
#pragma unroll
        for (int i = 0; i < 4; ++i) {
            int idx = tid + (i << 8);    // 0..1023
            int row = idx >> 3;          // 0..127
            int kq  = idx & 7;           // 8-halfword group
            // A: gate + convert in-register (c tile L1-hot, rt broadcast)
            f32x4 c0 = *(const f32x4*)(cw + (size_t)(m0 + row) * 64 + (kq << 3));
            f32x4 c1 = *(const f32x4*)(cw + (size_t)(m0 + row) * 64 + (kq << 3) + 4);
            float rv = rt[(size_t)(m0 + row) * 8 + e];
            bf16x8 pk;
#pragma unroll
            for (int j2 = 0; j2 < 4; ++j2) {
                pk[j2]     = (__bf16)(rv * c0[j2]);
                pk[4 + j2] = (__bf16)(rv * c1[j2]);
            }
            *(bf16x8*)(&sA[row][kq << 3]) = pk;
            // B: straight copy from L2-resident bc
            *(uint4*)(&sB[row][kq << 3]) =
                *(const uint4*)(bc + (size_t)(n0 + row) * GDIM + k0 + (kq << 3));
        }
        __syncthreads();
#pragma unroll
        for (int kk = 0; kk < 2; ++kk) {
            bf16x8 af[4], bfr[4];
#pragma unroll
            for (int i = 0; i < 4; ++i)
                af[i] = *(const bf16x8*)(&sA[mo + (i << 4) + l16][(kk << 5) + (quad << 3)]);
#pragma unroll
            for (int j = 0; j < 4; ++j)
                bfr[j] = *(const bf16x8*)(&sB[no + (j << 4) + l16][(kk << 5) + (quad << 3)]);
#pragma unroll
            for (int i = 0; i < 4; ++i)
#pragma unroll
                for (int j = 0; j < 4; ++j)
                    acc[i][j] = __builtin_amdgcn_mfma_f32_16x16x32_bf16(af[i], bfr[j], acc[i][j], 0, 0, 0);
        }
        __syncthreads();
    }

#pragma unroll
    for (int i = 0; i < 4; ++i)
#pragma unroll
        for (int j = 0; j < 4; ++j)
#pragma unroll
            for (int r = 0; r < 4; ++r) {
                int row = m0 + mo + (i << 4) + (quad << 2) + r;
                int col = n0 + no + (j << 4) + l16;
                y[(size_t)row * OUTD + col] = acc[i][j][r];
            }
}

extern "C" void kernel_launch(void* const* d_in, const int* in_sizes, int n_in,
                              void* d_out, int out_size, void* d_ws, size_t ws_size,
                              hipStream_t stream) {
    const float* x  = (const float*)d_in[0];   // [8,4096,1024]
    const float* rw = (const float*)d_in[1];   // [8,1024]
    const float* A  = (const float*)d_in[2];   // [64,1024]
    const float* B  = (const float*)d_in[3];   // [8,1024,64]
    float* y = (float*)d_out;                  // [8,4096,1024] fp32

    float* cw = (float*)d_ws;                          // [32768][64] f32
    float* rt = cw + (size_t)NTOK * 64;                // [32768][8] f32
    unsigned short* w1 = (unsigned short*)(rt + (size_t)NTOK * 8);  // [80][1024] bf16
    unsigned short* bc = w1 + NW1 * DIM;               // [1024][512] bf16

    conv_w1<<<(NW1 * DIM + 255) / 256, 256, 0, stream>>>(A, rw, w1);
    conv_b<<<(OUTD * GDIM + 255) / 256, 256, 0, stream>>>(B, bc);
    k1_route_compress<<<NTOK / 32, 256, 0, stream>>>(x, w1, cw, rt);
    k2_up<<<(NTOK / 128) * (OUTD / 128), 256, 0, stream>>>(cw, rt, bc, y);
}